// Round 2
// baseline (74.145 us; speedup 1.0000x reference)
//
#include <hip/hip_runtime.h>

constexpr int N = 512;   // number of samples
constexpr int D = 256;   // feature dim
#define MARGIN 1.0f

// Cross-block reduction state lives in module-scope globals, NOT the
// workspace: the harness poison-fills the entire 256 MiB workspace every
// iteration (the 40 us fill dispatch), which would destroy any ticket
// stored there. g_ticket starts at 0 (static init) and is re-armed to 0
// by the last block each iteration, so it is self-sustaining across
// graph replays.
__device__ float g_psum[N / 2];
__device__ float g_pcnt[N / 2];
__device__ int g_ticket = 0;

// Block b (1024 threads = 16 waves) owns TWO anchors i0=2b, i1=2b+1:
// each row r is loaded ONCE and used for both anchors' distances
// (d^2 = sum((a-b)^2)), halving L2/L1 traffic vs 1 anchor/block.
// 256 blocks -> 1 block/CU, 16 waves/CU. Then per-anchor: compact
// positives (t[j]==t[i], j!=i) and sum relu(c_j - d_ik) over (j,k).
// The final scalar reduction is folded in via a device-scope ticket:
// ONE dispatch total (the finalize kernel's launch gap was measurable).
#define ACC(S, A, B)                                                   \
  { float ex = A.x - B.x, ey = A.y - B.y, ez = A.z - B.z,              \
          ew = A.w - B.w;                                              \
    S += ex * ex + ey * ey + ez * ez + ew * ew; }

__global__ __launch_bounds__(1024, 4) void triplet_fused(
    const float* __restrict__ x, const int* __restrict__ tgt,
    float* __restrict__ out) {
  __shared__ __align__(16) float m0[N], m1[N];  // dist rows, +INF at positives
  __shared__ float cl0[N], cl1[N];              // compacted c = d_ap + margin
  __shared__ int nv0, nv1;
  __shared__ float wred[32];                    // 16 waves x {sum | cnt}
  __shared__ int lastf;

  const int b = blockIdx.x;
  const int i0 = 2 * b, i1 = 2 * b + 1;
  const int tid = threadIdx.x;                  // 1024 threads = 16 waves
  const int wave = tid >> 6, lane = tid & 63;
  const int sub = lane & 15, rg = lane >> 4;    // chunk-in-row, row-in-group
  const int t0 = tgt[i0], t1 = tgt[i1];

  if (tid == 0) { nv0 = 0; nv1 = 0; }

  // both anchors' row fragments, loop-invariant registers (L1-resident)
  const float4* xa = (const float4*)(x + (size_t)i0 * D);
  const float4* xc = (const float4*)(x + (size_t)i1 * D);
  float4 a0 = xa[sub], a1 = xa[16 + sub], a2 = xa[32 + sub], a3 = xa[48 + sub];
  float4 c0 = xc[sub], c1 = xc[16 + sub], c2 = xc[32 + sub], c3 = xc[48 + sub];
  __syncthreads();                              // nv zeroed

  // Wave w covers rows [w*32, w*32+32): 4 rows/iter (one per 16-lane group).
  // Per-block rotation decorrelates the blocks' L2 streams.
  const int rot = (b * 171) & (N - 1);
  const int rbase = wave * 32 + rg;
  #pragma unroll 2
  for (int it = 0; it < 8; ++it) {
    const int r = (rbase + it * 4 + rot) & (N - 1);
    const float4* xr = (const float4*)(x + (size_t)r * D);
    float4 b0 = xr[sub];
    float4 b1 = xr[16 + sub];
    float4 b2 = xr[32 + sub];
    float4 b3 = xr[48 + sub];
    float sa = 0.f, sb = 0.f;                   // d^2 partials, both anchors
    ACC(sa, a0, b0); ACC(sa, a1, b1); ACC(sa, a2, b2); ACC(sa, a3, b3);
    ACC(sb, c0, b0); ACC(sb, c1, b1); ACC(sb, c2, b2); ACC(sb, c3, b3);
    // reduce over the 16-lane group (lane sub==0 gets clean value)
    #pragma unroll
    for (int off = 8; off > 0; off >>= 1) {
      sa += __shfl_down(sa, off);
      sb += __shfl_down(sb, off);
    }
    if (sub == 0) {
      const int tj = tgt[r];
      float da = sqrtf(fmaxf(sa, 1e-16f));
      float db = sqrtf(fmaxf(sb, 1e-16f));
      m0[r] = (tj != t0) ? da : __builtin_inff();
      m1[r] = (tj != t1) ? db : __builtin_inff();
      if (tj == t0 && r != i0) { int s = atomicAdd(&nv0, 1); cl0[s] = da + MARGIN; }
      if (tj == t1 && r != i1) { int s = atomicAdd(&nv1, 1); cl1[s] = db + MARGIN; }
    }
  }
  __syncthreads();

  // triplet phase: thread pair (tid, tid+512) shares element e=tid&511 and
  // splits each clist between them (v = half, half+2, ...)
  float sum = 0.f, cnt = 0.f;
  const int e = tid & 511, half = tid >> 9;
  const float mk0 = m0[e], mk1 = m1[e];
  const int n0 = nv0, n1 = nv1;
  for (int v = half; v < n0; v += 2) {
    float a = cl0[v] - mk0;                     // cl0[v] is LDS broadcast
    sum += fmaxf(a, 0.f);
    cnt += (a > 1e-16f ? 1.f : 0.f);
  }
  for (int v = half; v < n1; v += 2) {
    float a = cl1[v] - mk1;
    sum += fmaxf(a, 0.f);
    cnt += (a > 1e-16f ? 1.f : 0.f);
  }

  // block reduction over 16 waves
  #pragma unroll
  for (int off = 32; off > 0; off >>= 1) {
    sum += __shfl_down(sum, off);
    cnt += __shfl_down(cnt, off);
  }
  if (lane == 0) { wred[wave] = sum; wred[16 + wave] = cnt; }
  __syncthreads();
  if (tid == 0) {
    float s = 0.f, c = 0.f;
    #pragma unroll
    for (int w = 0; w < 16; ++w) { s += wred[w]; c += wred[16 + w]; }
    g_psum[b] = s;
    g_pcnt[b] = c;
    __threadfence();                            // publish partials (release)
    const int old = atomicAdd(&g_ticket, 1);    // device-scope
    lastf = (old == N / 2 - 1) ? 1 : 0;
  }
  __syncthreads();                              // lastf uniform; wred reusable

  // last arriving block folds the 256 partials and re-arms the ticket
  if (lastf) {
    __threadfence();                            // acquire side
    float s = (tid < N / 2) ? g_psum[tid] : 0.f;
    float c = (tid < N / 2) ? g_pcnt[tid] : 0.f;
    #pragma unroll
    for (int off = 32; off > 0; off >>= 1) {
      s += __shfl_down(s, off);
      c += __shfl_down(c, off);
    }
    if (lane == 0) { wred[wave] = s; wred[16 + wave] = c; }
    __syncthreads();
    if (tid == 0) {
      float ts = 0.f, tc = 0.f;
      #pragma unroll
      for (int w = 0; w < 16; ++w) { ts += wred[w]; tc += wred[16 + w]; }
      out[0] = ts / (tc + 1e-16f);
      atomicExch(&g_ticket, 0);                 // re-arm for next replay
    }
  }
}

extern "C" void kernel_launch(void* const* d_in, const int* in_sizes, int n_in,
                              void* d_out, int out_size, void* d_ws, size_t ws_size,
                              hipStream_t stream) {
  const float* x = (const float*)d_in[0];   // [512, 256] fp32
  const int* tgt = (const int*)d_in[1];     // [512] int32
  float* out = (float*)d_out;               // scalar fp32
  (void)d_ws; (void)ws_size;                // workspace unused (it is poisoned
                                            // every iteration; state lives in
                                            // __device__ globals instead)

  triplet_fused<<<N / 2, 1024, 0, stream>>>(x, tgt, out);
}

// Round 4
// 64.869 us; speedup vs baseline: 1.1430x; 1.1430x over previous
//
#include <hip/hip_runtime.h>

constexpr int N = 512;   // number of samples
constexpr int D = 256;   // feature dim
#define MARGIN 1.0f

// 16-lane (DPP "row") sum reduction on the VALU pipe: 4 dependent
// v_add with row_shr — replaces 4 dependent ds_bpermute (__shfl_down,
// LDS pipe ~30cy each) with ~4cy VALU ops.
// row_shr:N reads lane i-N  =>  the tree accumulates UPWARD and the
// complete row sum lands in the LAST lane of each 16-group (sub==15).
// (Round-3 bug: read at sub==0, which only holds its own partial.)
__device__ __forceinline__ float dpp_add16(float v) {
  // row_shr:n ctrl = 0x110 | n; row_mask=0xF bank_mask=0xF bound_ctrl=1
  // (out-of-row reads return 0 -> safe to add unconditionally)
  v += __int_as_float(__builtin_amdgcn_update_dpp(
      0, __float_as_int(v), 0x118, 0xF, 0xF, true));
  v += __int_as_float(__builtin_amdgcn_update_dpp(
      0, __float_as_int(v), 0x114, 0xF, 0xF, true));
  v += __int_as_float(__builtin_amdgcn_update_dpp(
      0, __float_as_int(v), 0x112, 0xF, 0xF, true));
  v += __int_as_float(__builtin_amdgcn_update_dpp(
      0, __float_as_int(v), 0x111, 0xF, 0xF, true));
  return v;
}

// Block b (1024 threads = 16 waves) owns TWO anchors i0=2b, i1=2b+1:
// each row r is loaded ONCE and used for both anchors' distances,
// halving L2 traffic vs 1 anchor/block. 256 blocks -> 1 block/CU.
// Inner loop is software-pipelined: iteration i+1's four float4 row
// fragments are issued before iteration i's compute, hiding the ~200cy
// L2 hit latency under the ~130cy of distance VALU work.
#define ACC(S, A, B)                                                   \
  { float ex = A.x - B.x, ey = A.y - B.y, ez = A.z - B.z,              \
          ew = A.w - B.w;                                              \
    S += ex * ex + ey * ey + ez * ez + ew * ew; }

__global__ __launch_bounds__(1024, 4) void triplet_fused(
    const float* __restrict__ x, const int* __restrict__ tgt,
    float* __restrict__ part) {
  __shared__ __align__(16) float m0[N], m1[N];  // dist rows, +INF at positives
  __shared__ float cl0[N], cl1[N];              // compacted c = d_ap + margin
  __shared__ int ts[N];                         // targets, staged once
  __shared__ int nv0, nv1;
  __shared__ float wred[32];                    // 16 waves x {sum | cnt}

  const int b = blockIdx.x;
  const int i0 = 2 * b, i1 = 2 * b + 1;
  const int tid = threadIdx.x;                  // 1024 threads = 16 waves
  const int wave = tid >> 6, lane = tid & 63;
  const int sub = lane & 15, rg = lane >> 4;    // chunk-in-row, row-in-group

  if (tid == 0) { nv0 = 0; nv1 = 0; }
  if (tid < N) ts[tid] = tgt[tid];              // one coalesced pass

  // both anchors' row fragments, loop-invariant registers
  const float4* xa = (const float4*)(x + (size_t)i0 * D);
  const float4* xc = (const float4*)(x + (size_t)i1 * D);
  float4 a0 = xa[sub], a1 = xa[16 + sub], a2 = xa[32 + sub], a3 = xa[48 + sub];
  float4 c0 = xc[sub], c1 = xc[16 + sub], c2 = xc[32 + sub], c3 = xc[48 + sub];
  __syncthreads();                              // nv zeroed, ts ready
  const int t0 = ts[i0], t1 = ts[i1];

  // Wave w covers rows [w*32, w*32+32): 4 rows/iter (one per 16-lane group).
  // Per-block rotation decorrelates the blocks' L2 streams.
  const int rot = (b * 171) & (N - 1);
  const int rbase = wave * 32 + rg;

  // prologue: load iteration 0's row
  int r = (rbase + rot) & (N - 1);
  const float4* xr = (const float4*)(x + (size_t)r * D);
  float4 b0 = xr[sub], b1 = xr[16 + sub], b2 = xr[32 + sub], b3 = xr[48 + sub];

  #pragma unroll 2
  for (int it = 0; it < 8; ++it) {
    // issue next iteration's loads first (wraps to a warm row on it==7)
    const int rn = (rbase + (((it + 1) & 7) << 2) + rot) & (N - 1);
    const float4* xn = (const float4*)(x + (size_t)rn * D);
    float4 p0 = xn[sub], p1 = xn[16 + sub], p2 = xn[32 + sub], p3 = xn[48 + sub];

    float sa = 0.f, sb = 0.f;                   // d^2 partials, both anchors
    ACC(sa, a0, b0); ACC(sa, a1, b1); ACC(sa, a2, b2); ACC(sa, a3, b3);
    ACC(sb, c0, b0); ACC(sb, c1, b1); ACC(sb, c2, b2); ACC(sb, c3, b3);
    sa = dpp_add16(sa);                         // VALU-pipe 16-lane reduce
    sb = dpp_add16(sb);
    if (sub == 15) {                            // row sum lands in LAST lane
      const int tj = ts[r];
      float da = sqrtf(fmaxf(sa, 1e-16f));
      float db = sqrtf(fmaxf(sb, 1e-16f));
      m0[r] = (tj != t0) ? da : __builtin_inff();
      m1[r] = (tj != t1) ? db : __builtin_inff();
      if (tj == t0 && r != i0) { int s = atomicAdd(&nv0, 1); cl0[s] = da + MARGIN; }
      if (tj == t1 && r != i1) { int s = atomicAdd(&nv1, 1); cl1[s] = db + MARGIN; }
    }
    b0 = p0; b1 = p1; b2 = p2; b3 = p3;         // rotate pipeline
    r = rn;
  }
  __syncthreads();

  // triplet phase: thread pair (tid, tid+512) shares element e=tid&511 and
  // splits each clist between them (v = half, half+2, ...)
  float sum = 0.f, cnt = 0.f;
  const int e = tid & 511, half = tid >> 9;
  const float mk0 = m0[e], mk1 = m1[e];
  const int n0 = nv0, n1 = nv1;
  for (int v = half; v < n0; v += 2) {
    float a = cl0[v] - mk0;                     // cl0[v] is LDS broadcast
    sum += fmaxf(a, 0.f);
    cnt += (a > 1e-16f ? 1.f : 0.f);
  }
  for (int v = half; v < n1; v += 2) {
    float a = cl1[v] - mk1;
    sum += fmaxf(a, 0.f);
    cnt += (a > 1e-16f ? 1.f : 0.f);
  }

  // block reduction over 16 waves, one partial pair per block
  #pragma unroll
  for (int off = 32; off > 0; off >>= 1) {
    sum += __shfl_down(sum, off);
    cnt += __shfl_down(cnt, off);
  }
  if (lane == 0) { wred[wave] = sum; wred[16 + wave] = cnt; }
  __syncthreads();
  if (tid == 0) {
    float s = 0.f, c = 0.f;
    #pragma unroll
    for (int w = 0; w < 16; ++w) { s += wred[w]; c += wred[16 + w]; }
    part[2 * b] = s;
    part[2 * b + 1] = c;
  }
}

// Reduce 256 (sum,cnt) partials and divide.
__global__ __launch_bounds__(256) void triplet_finalize(
    const float* __restrict__ part, float* __restrict__ out) {
  __shared__ float wred[8];
  const int tid = threadIdx.x;
  float s = part[2 * tid], c = part[2 * tid + 1];
  #pragma unroll
  for (int off = 32; off > 0; off >>= 1) {
    s += __shfl_down(s, off);
    c += __shfl_down(c, off);
  }
  int wave = tid >> 6, lane = tid & 63;
  if (lane == 0) { wred[wave] = s; wred[4 + wave] = c; }
  __syncthreads();
  if (tid == 0) {
    float ts = wred[0] + wred[1] + wred[2] + wred[3];
    float tc = wred[4] + wred[5] + wred[6] + wred[7];
    out[0] = ts / (tc + 1e-16f);
  }
}

extern "C" void kernel_launch(void* const* d_in, const int* in_sizes, int n_in,
                              void* d_out, int out_size, void* d_ws, size_t ws_size,
                              hipStream_t stream) {
  const float* x = (const float*)d_in[0];   // [512, 256] fp32
  const int* tgt = (const int*)d_in[1];     // [512] int32
  float* out = (float*)d_out;               // scalar fp32
  float* part = (float*)d_ws;               // 256 x {sum, cnt} partials

  triplet_fused<<<N / 2, 1024, 0, stream>>>(x, tgt, part);
  triplet_finalize<<<1, 256, 0, stream>>>(part, out);
}